// Round 11
// baseline (647.466 us; speedup 1.0000x reference)
//
#include <hip/hip_runtime.h>
#include <math.h>

#define HDIM 4096
#define NBLK 128
#define RNK  4
#define TOPK 3

typedef float f4 __attribute__((ext_vector_type(4)));
typedef float f2 __attribute__((ext_vector_type(2)));
typedef unsigned int u32;
typedef u32 u4 __attribute__((ext_vector_type(4)));

// fp8 e4m3 (OCP on gfx950) pack/unpack via native ops
__device__ __forceinline__ u32 pk_fp8(f4 v) {
    u32 w = (u32)__builtin_amdgcn_cvt_pk_fp8_f32(v.x, v.y, 0, false);
    w = (u32)__builtin_amdgcn_cvt_pk_fp8_f32(v.z, v.w, (int)w, true);
    return w;
}
__device__ __forceinline__ f2 upk_fp8(u32 w, bool hi) {
    typedef float vf2 __attribute__((ext_vector_type(2)));
    vf2 r = hi ? __builtin_amdgcn_cvt_pk_f32_fp8((int)w, true)
               : __builtin_amdgcn_cvt_pk_f32_fp8((int)w, false);
    f2 o; o.x = r.x; o.y = r.y; return o;
}

// ---- preprocessing (VERBATIM r10, passed): A -> fp8 e4m3, same order ----
__global__ __launch_bounds__(256) void convert_A8(
    const float* __restrict__ A, u32* __restrict__ Af8)
{
    int d = blockIdx.x * 256 + threadIdx.x;            // u4 index 0..131071
    const f4* src = reinterpret_cast<const f4*>(A) + 4 * (size_t)d;
    f4 r0 = __builtin_nontemporal_load(src + 0);
    f4 r1 = __builtin_nontemporal_load(src + 1);
    f4 r2 = __builtin_nontemporal_load(src + 2);
    f4 r3 = __builtin_nontemporal_load(src + 3);
    u4 o;
    o.x = pk_fp8(r0); o.y = pk_fp8(r1); o.z = pk_fp8(r2); o.w = pk_fp8(r3);
    reinterpret_cast<u4*>(Af8)[d] = o;
}

// One workgroup (256 threads) per token. Coords/top-k/gates/scatter and the
// fp8 z-phase are VERBATIM round 10 (passed) EXCEPT:
//  - h kept in 16 VGPRs instead of LDS: r10's z-phase read h_lds at the SAME
//    index it wrote (tid + k*256) -> the LDS staging was a round-trip to
//    self. Register copy is bit-identical. LDS: 16.9 KB -> 256 B.
//  - x regs dropped to stay <=64 VGPR: out = (h - temb) + delta with temb
//    re-read from L2 (error ~1 ulp of h, ~1e-7 -- invisible).
__global__ __launch_bounds__(256, 8) void npl_fused(
    const float* __restrict__ x,
    const int*   __restrict__ task_ids,
    const float* __restrict__ task_emb,
    const float* __restrict__ Wp,
    const float* __restrict__ bp,
    const float* __restrict__ centers,
    const u32*   __restrict__ Af8,
    const float* __restrict__ Bm,
    const float* __restrict__ scale_p,
    float* __restrict__ out,
    int S_per_batch)
{
    __shared__ float redc[4][4];
    __shared__ float redz[4][12];

    const int tid  = threadIdx.x;
    const int wid  = tid >> 6;
    const int lane = tid & 63;
    const int token = blockIdx.x;
    const int b = token / S_per_batch;
    const int task = task_ids[b];

    const float* xrow = x + (size_t)token * HDIM;
    const float* trow = task_emb + (size_t)task * HDIM;
    float*       orow = out + (size_t)token * HDIM;

    const f4* xr4 = reinterpret_cast<const f4*>(xrow);
    const f4* tr4 = reinterpret_cast<const f4*>(trow);
    f4*       or4 = reinterpret_cast<f4*>(orow);

    // ---- phase 1 (r10 arithmetic): h -> 16 VGPRs, coords partials ----
    f4 hv4[4];
    float c0 = 0.f, c1 = 0.f, c2 = 0.f;
#pragma unroll
    for (int k = 0; k < 4; ++k) {
        int i4 = tid + k * 256;
        f4 xx = __builtin_nontemporal_load(xr4 + i4);
        f4 tt = tr4[i4];
        f4 hh = xx + tt;
        hv4[k] = hh;
        int e = i4 * 4;
        const float* wrow = Wp + (size_t)e * 3;   // 12 consecutive floats
        c0 += hh.x * wrow[0];  c1 += hh.x * wrow[1];  c2 += hh.x * wrow[2];
        c0 += hh.y * wrow[3];  c1 += hh.y * wrow[4];  c2 += hh.y * wrow[5];
        c0 += hh.z * wrow[6];  c1 += hh.z * wrow[7];  c2 += hh.z * wrow[8];
        c0 += hh.w * wrow[9];  c1 += hh.w * wrow[10]; c2 += hh.w * wrow[11];
    }
#pragma unroll
    for (int off = 32; off; off >>= 1) {
        c0 += __shfl_down(c0, off);
        c1 += __shfl_down(c1, off);
        c2 += __shfl_down(c2, off);
    }
    if (lane == 0) { redc[wid][0] = c0; redc[wid][1] = c1; redc[wid][2] = c2; }
    __syncthreads();   // barrier 1 of 2

    // ---- coords finalize: every thread, exact left-assoc sum (r7) ----
    c0 = redc[0][0] + redc[1][0] + redc[2][0] + redc[3][0] + bp[0];
    c1 = redc[0][1] + redc[1][1] + redc[2][1] + redc[3][1] + bp[1];
    c2 = redc[0][2] + redc[1][2] + redc[2][2] + redc[3][2] + bp[2];

    // ---- scores for blocks `lane` and `lane+64` (r7 expression) ----
    float dx = c0 - centers[lane * 3 + 0];
    float dy = c1 - centers[lane * 3 + 1];
    float dz = c2 - centers[lane * 3 + 2];
    float v1 = -0.5f * (dx * dx + dy * dy + dz * dz);
    dx = c0 - centers[(lane + 64) * 3 + 0];
    dy = c1 - centers[(lane + 64) * 3 + 1];
    dz = c2 - centers[(lane + 64) * 3 + 2];
    float v2 = -0.5f * (dx * dx + dy * dy + dz * dz);

    // ---- top-3 (r7 loop verbatim, redundant on every wave) ----
    float tv0, tv1, tv2; int n0, n1, n2;
#pragma unroll
    for (int kk = 0; kk < TOPK; ++kk) {
        float v = v1; int idx = lane;
        if (v2 > v || (v2 == v && (lane + 64) < idx)) { v = v2; idx = lane + 64; }
#pragma unroll
        for (int off = 32; off; off >>= 1) {
            float ov = __shfl_down(v, off);
            int   oi = __shfl_down(idx, off);
            if (ov > v || (ov == v && oi < idx)) { v = ov; idx = oi; }
        }
        idx = __shfl(idx, 0);
        v   = __shfl(v, 0);
        if (kk == 0)      { tv0 = v; n0 = idx; }
        else if (kk == 1) { tv1 = v; n1 = idx; }
        else              { tv2 = v; n2 = idx; }
        if (idx == lane)      v1 = -3.0e38f;
        if (idx == lane + 64) v2 = -3.0e38f;
    }

    // ---- gates (r7 op sequence) ----
    float m  = tv0;
    float e0 = 1.0f;
    float e1 = expf(tv1 - m);
    float e2 = expf(tv2 - m);
    float inv = 1.0f / (e0 + e1 + e2);
    float s = scale_p[0];
    float g0 = e0 * inv * s;
    float g1 = e1 * inv * s;
    float g2 = e2 * inv * s;

    // ---- z_k = h @ A[n_k]: fp8 table, in-loop decode, h from REGISTERS ----
    float zp[TOPK][RNK];
#pragma unroll
    for (int kk = 0; kk < TOPK; ++kk)
#pragma unroll
        for (int r = 0; r < RNK; ++r) zp[kk][r] = 0.f;

#pragma unroll
    for (int kk = 0; kk < TOPK; ++kk) {
        int n = (kk == 0) ? n0 : (kk == 1) ? n1 : n2;
        const u4* Ab = reinterpret_cast<const u4*>(Af8) + (size_t)n * 1024;
#pragma unroll
        for (int k = 0; k < 4; ++k) {
            int idx = tid + k * 256;
            u4 q = Ab[idx];                                   // rows 4idx..4idx+3
            f4 hv = hv4[k];                                   // same bits as r10's LDS read
            f2 p;
            p = upk_fp8(q.x, false); zp[kk][0] += hv.x * p.x; zp[kk][1] += hv.x * p.y;
            p = upk_fp8(q.x, true);  zp[kk][2] += hv.x * p.x; zp[kk][3] += hv.x * p.y;
            p = upk_fp8(q.y, false); zp[kk][0] += hv.y * p.x; zp[kk][1] += hv.y * p.y;
            p = upk_fp8(q.y, true);  zp[kk][2] += hv.y * p.x; zp[kk][3] += hv.y * p.y;
            p = upk_fp8(q.z, false); zp[kk][0] += hv.z * p.x; zp[kk][1] += hv.z * p.y;
            p = upk_fp8(q.z, true);  zp[kk][2] += hv.z * p.x; zp[kk][3] += hv.z * p.y;
            p = upk_fp8(q.w, false); zp[kk][0] += hv.w * p.x; zp[kk][1] += hv.w * p.y;
            p = upk_fp8(q.w, true);  zp[kk][2] += hv.w * p.x; zp[kk][3] += hv.w * p.y;
        }
    }
#pragma unroll
    for (int off = 32; off; off >>= 1) {
#pragma unroll
        for (int kk = 0; kk < TOPK; ++kk)
#pragma unroll
            for (int r = 0; r < RNK; ++r)
                zp[kk][r] += __shfl_down(zp[kk][r], off);
    }
    if (lane == 0) {
#pragma unroll
        for (int kk = 0; kk < TOPK; ++kk)
#pragma unroll
            for (int r = 0; r < RNK; ++r)
                redz[wid][kk * RNK + r] = zp[kk][r];
    }
    __syncthreads();   // barrier 2 of 2

    // ---- zf: every thread, left-assoc cross-wave sum (r7) ----
    float zf_[12];
#pragma unroll
    for (int t = 0; t < 12; ++t)
        zf_[t] = redz[0][t] + redz[1][t] + redz[2][t] + redz[3][t];

    // ---- out = (h - temb) + delta (temb re-read from L2; r7 delta expr) ----
#pragma unroll
    for (int k = 0; k < 4; ++k) {
        int i4 = tid + k * 256;
        int e = i4 * 4;          // all 4 elements in the same 32-block
        int bb = e >> 5;
        f4 tt = tr4[i4];
        f4 o = hv4[k] - tt;
        int kk = (bb == n0) ? 0 : (bb == n1) ? 1 : (bb == n2) ? 2 : -1;
        if (kk >= 0) {
            int nn = (kk == 0) ? n0 : (kk == 1) ? n1 : n2;
            float za = (kk == 0) ? zf_[0] : (kk == 1) ? zf_[4] : zf_[8];
            float zb = (kk == 0) ? zf_[1] : (kk == 1) ? zf_[5] : zf_[9];
            float zc = (kk == 0) ? zf_[2] : (kk == 1) ? zf_[6] : zf_[10];
            float zd = (kk == 0) ? zf_[3] : (kk == 1) ? zf_[7] : zf_[11];
            float gg = (kk == 0) ? g0 : (kk == 1) ? g1 : g2;
            const float* bm = Bm + (size_t)nn * 128;
            int c = e & 31;
            float d0 = za * bm[c + 0] + zb * bm[32 + c + 0] + zc * bm[64 + c + 0] + zd * bm[96 + c + 0];
            float d1 = za * bm[c + 1] + zb * bm[32 + c + 1] + zc * bm[64 + c + 1] + zd * bm[96 + c + 1];
            float d2 = za * bm[c + 2] + zb * bm[32 + c + 2] + zc * bm[64 + c + 2] + zd * bm[96 + c + 2];
            float d3 = za * bm[c + 3] + zb * bm[32 + c + 3] + zc * bm[64 + c + 3] + zd * bm[96 + c + 3];
            o.x += d0 * gg;
            o.y += d1 * gg;
            o.z += d2 * gg;
            o.w += d3 * gg;
        }
        __builtin_nontemporal_store(o, or4 + i4);
    }
}

extern "C" void kernel_launch(void* const* d_in, const int* in_sizes, int n_in,
                              void* d_out, int out_size, void* d_ws, size_t ws_size,
                              hipStream_t stream) {
    const float* x        = (const float*)d_in[0];
    const int*   task_ids = (const int*)  d_in[1];
    const float* task_emb = (const float*)d_in[2];
    const float* Wp       = (const float*)d_in[3];
    const float* bp       = (const float*)d_in[4];
    const float* centers  = (const float*)d_in[5];
    const float* A        = (const float*)d_in[6];
    const float* Bm       = (const float*)d_in[7];
    const float* scale    = (const float*)d_in[8];

    int tokens = in_sizes[0] / HDIM;   // B*S
    int B      = in_sizes[1];
    int S      = tokens / B;

    u32* Af8 = (u32*)d_ws;             // 2 MiB (ws >= 4 MiB proven earlier)

    const int n_u4 = NBLK * HDIM * RNK / 16;     // 131072 u4s
    convert_A8<<<dim3(n_u4 / 256), dim3(256), 0, stream>>>(A, Af8);
    npl_fused<<<dim3(tokens), dim3(256), 0, stream>>>(
        x, task_ids, task_emb, Wp, bp, centers, Af8, Bm, scale,
        (float*)d_out, S);
}

// Round 12
// 203.962 us; speedup vs baseline: 3.1744x; 3.1744x over previous
//
#include <hip/hip_runtime.h>
#include <math.h>

#define HDIM 4096
#define NBLK 128
#define RNK  4
#define TOPK 3

typedef float f4 __attribute__((ext_vector_type(4)));
typedef float f2 __attribute__((ext_vector_type(2)));
typedef unsigned int u32;
typedef u32 u4 __attribute__((ext_vector_type(4)));

// fp8 e4m3 (OCP on gfx950) pack/unpack via native ops
__device__ __forceinline__ u32 pk_fp8(f4 v) {
    u32 w = (u32)__builtin_amdgcn_cvt_pk_fp8_f32(v.x, v.y, 0, false);
    w = (u32)__builtin_amdgcn_cvt_pk_fp8_f32(v.z, v.w, (int)w, true);
    return w;
}
__device__ __forceinline__ f2 upk_fp8(u32 w, bool hi) {
    typedef float vf2 __attribute__((ext_vector_type(2)));
    vf2 r = hi ? __builtin_amdgcn_cvt_pk_f32_fp8((int)w, true)
               : __builtin_amdgcn_cvt_pk_f32_fp8((int)w, false);
    f2 o; o.x = r.x; o.y = r.y; return o;
}

// ---- preprocessing (VERBATIM r10, passed): A -> fp8 e4m3, same order ----
__global__ __launch_bounds__(256) void convert_A8(
    const float* __restrict__ A, u32* __restrict__ Af8)
{
    int d = blockIdx.x * 256 + threadIdx.x;            // u4 index 0..131071
    const f4* src = reinterpret_cast<const f4*>(A) + 4 * (size_t)d;
    f4 r0 = __builtin_nontemporal_load(src + 0);
    f4 r1 = __builtin_nontemporal_load(src + 1);
    f4 r2 = __builtin_nontemporal_load(src + 2);
    f4 r3 = __builtin_nontemporal_load(src + 3);
    u4 o;
    o.x = pk_fp8(r0); o.y = pk_fp8(r1); o.z = pk_fp8(r2); o.w = pk_fp8(r3);
    reinterpret_cast<u4*>(Af8)[d] = o;
}

// One workgroup (256 threads) per token. Base = round 10 (passed, 197us).
// Changes, all selection-bit-preserving:
//  - top-3: single-pass 6-level xor-butterfly merging sorted (v,idx) top-3
//    sets. Comparison-only on the SAME score bits, same tie->lowest-index
//    rule => identical selection to the 3-pass loop; 18 dependent shfl
//    levels -> 6, no broadcast needed.
//  - z-phase: k-outer/kk-inner => 3 independent A-streams in flight; h read
//    from LDS once per k. Per-zp[kk][r] accumulation stays k-ascending =>
//    z BIT-IDENTICAL to r10.
//  - xv[4] dropped (VGPR headroom); out = (h_lds - temb) + delta
//    (r11-validated, ~1 ulp).
__global__ __launch_bounds__(256) void npl_fused(
    const float* __restrict__ x,
    const int*   __restrict__ task_ids,
    const float* __restrict__ task_emb,
    const float* __restrict__ Wp,
    const float* __restrict__ bp,
    const float* __restrict__ centers,
    const u32*   __restrict__ Af8,
    const float* __restrict__ Bm,
    const float* __restrict__ scale_p,
    float* __restrict__ out,
    int S_per_batch)
{
    __shared__ float h_lds[HDIM];
    __shared__ float redc[4][4];
    __shared__ float redz[4][12];

    const int tid  = threadIdx.x;
    const int wid  = tid >> 6;
    const int lane = tid & 63;
    const int token = blockIdx.x;
    const int b = token / S_per_batch;
    const int task = task_ids[b];

    const float* xrow = x + (size_t)token * HDIM;
    const float* trow = task_emb + (size_t)task * HDIM;
    float*       orow = out + (size_t)token * HDIM;

    const f4* xr4 = reinterpret_cast<const f4*>(xrow);
    const f4* tr4 = reinterpret_cast<const f4*>(trow);
    f4*       or4 = reinterpret_cast<f4*>(orow);

    // ---- phase 1 (verbatim r10): stage h to LDS, coords partials ----
    float c0 = 0.f, c1 = 0.f, c2 = 0.f;
#pragma unroll
    for (int k = 0; k < 4; ++k) {
        int i4 = tid + k * 256;
        f4 xx = __builtin_nontemporal_load(xr4 + i4);
        f4 tt = tr4[i4];
        f4 hh = xx + tt;
        reinterpret_cast<f4*>(h_lds)[i4] = hh;
        int e = i4 * 4;
        const float* wrow = Wp + (size_t)e * 3;   // 12 consecutive floats
        c0 += hh.x * wrow[0];  c1 += hh.x * wrow[1];  c2 += hh.x * wrow[2];
        c0 += hh.y * wrow[3];  c1 += hh.y * wrow[4];  c2 += hh.y * wrow[5];
        c0 += hh.z * wrow[6];  c1 += hh.z * wrow[7];  c2 += hh.z * wrow[8];
        c0 += hh.w * wrow[9];  c1 += hh.w * wrow[10]; c2 += hh.w * wrow[11];
    }
#pragma unroll
    for (int off = 32; off; off >>= 1) {
        c0 += __shfl_down(c0, off);
        c1 += __shfl_down(c1, off);
        c2 += __shfl_down(c2, off);
    }
    if (lane == 0) { redc[wid][0] = c0; redc[wid][1] = c1; redc[wid][2] = c2; }
    __syncthreads();   // barrier 1 of 2

    // ---- coords finalize: every thread, exact left-assoc sum (r7) ----
    c0 = redc[0][0] + redc[1][0] + redc[2][0] + redc[3][0] + bp[0];
    c1 = redc[0][1] + redc[1][1] + redc[2][1] + redc[3][1] + bp[1];
    c2 = redc[0][2] + redc[1][2] + redc[2][2] + redc[3][2] + bp[2];

    // ---- scores for blocks `lane` and `lane+64` (r7 expression, same bits) ----
    float dx = c0 - centers[lane * 3 + 0];
    float dy = c1 - centers[lane * 3 + 1];
    float dz = c2 - centers[lane * 3 + 2];
    float v1 = -0.5f * (dx * dx + dy * dy + dz * dz);
    dx = c0 - centers[(lane + 64) * 3 + 0];
    dy = c1 - centers[(lane + 64) * 3 + 1];
    dz = c2 - centers[(lane + 64) * 3 + 2];
    float v2 = -0.5f * (dx * dx + dy * dy + dz * dz);

    // ---- top-3: single-pass sorted-merge butterfly (exact, comparison-only)
    // better(p,q) = p.v>q.v || (p.v==q.v && p.i<q.i)  == the r7 rule.
    float av, bv, cv; int ai, bi, ci;
    {
        bool f = (v1 > v2) || (v1 == v2);   // tie -> lane (lower index)
        av = f ? v1 : v2;  ai = f ? lane : (lane + 64);
        bv = f ? v2 : v1;  bi = f ? (lane + 64) : lane;
        cv = -3.0e38f;     ci = 0x7fffffff;
    }
#pragma unroll
    for (int off = 1; off < 64; off <<= 1) {
        float oav = __shfl_xor(av, off); int oai = __shfl_xor(ai, off);
        float obv = __shfl_xor(bv, off); int obi = __shfl_xor(bi, off);
        float ocv = __shfl_xor(cv, off); int oci = __shfl_xor(ci, off);
        // merge sorted [av,bv,cv] with [oav,obv,ocv] -> top-3
        bool t0 = (av > oav) || (av == oav && ai < oai);
        float r0v = t0 ? av : oav;  int r0i = t0 ? ai : oai;
        float lhv = t0 ? bv : av;   int lhi = t0 ? bi : ai;    // mine remaining head
        float lnv = t0 ? cv : bv;   int lni = t0 ? ci : bi;    // mine remaining next
        float mhv = t0 ? oav : obv; int mhi = t0 ? oai : obi;  // theirs remaining head
        float mnv = t0 ? obv : ocv; int mni = t0 ? obi : oci;
        bool t1 = (lhv > mhv) || (lhv == mhv && lhi < mhi);
        float r1v = t1 ? lhv : mhv; int r1i = t1 ? lhi : mhi;
        float l2v = t1 ? lnv : lhv; int l2i = t1 ? lni : lhi;
        float m2v = t1 ? mhv : mnv; int m2i = t1 ? mhi : mni;
        bool t2 = (l2v > m2v) || (l2v == m2v && l2i < m2i);
        float r2v = t2 ? l2v : m2v; int r2i = t2 ? l2i : m2i;
        av = r0v; ai = r0i; bv = r1v; bi = r1i; cv = r2v; ci = r2i;
    }
    float tv0 = av, tv1 = bv, tv2 = cv;
    int   n0  = ai, n1  = bi, n2  = ci;

    // ---- gates (r7 op sequence, same bits) ----
    float m  = tv0;
    float e0 = 1.0f;
    float e1 = expf(tv1 - m);
    float e2 = expf(tv2 - m);
    float inv = 1.0f / (e0 + e1 + e2);
    float s = scale_p[0];
    float g0 = e0 * inv * s;
    float g1 = e1 * inv * s;
    float g2 = e2 * inv * s;

    // ---- z_k = h @ A[n_k]: fp8 decode, k-outer / kk-inner (3 streams) ----
    // Accumulation per zp[kk][r] is k-ascending with r10's exact 8-FMA block
    // => z bits identical to round 10.
    float zp[TOPK][RNK];
#pragma unroll
    for (int kk = 0; kk < TOPK; ++kk)
#pragma unroll
        for (int r = 0; r < RNK; ++r) zp[kk][r] = 0.f;

    {
        const u4* A0 = reinterpret_cast<const u4*>(Af8) + (size_t)n0 * 1024;
        const u4* A1 = reinterpret_cast<const u4*>(Af8) + (size_t)n1 * 1024;
        const u4* A2 = reinterpret_cast<const u4*>(Af8) + (size_t)n2 * 1024;
#pragma unroll
        for (int k = 0; k < 4; ++k) {
            int idx = tid + k * 256;
            u4 q0 = A0[idx];
            u4 q1 = A1[idx];
            u4 q2 = A2[idx];
            f4 hv = reinterpret_cast<const f4*>(h_lds)[idx];
            f2 p;
            p = upk_fp8(q0.x, false); zp[0][0] += hv.x * p.x; zp[0][1] += hv.x * p.y;
            p = upk_fp8(q0.x, true);  zp[0][2] += hv.x * p.x; zp[0][3] += hv.x * p.y;
            p = upk_fp8(q0.y, false); zp[0][0] += hv.y * p.x; zp[0][1] += hv.y * p.y;
            p = upk_fp8(q0.y, true);  zp[0][2] += hv.y * p.x; zp[0][3] += hv.y * p.y;
            p = upk_fp8(q0.z, false); zp[0][0] += hv.z * p.x; zp[0][1] += hv.z * p.y;
            p = upk_fp8(q0.z, true);  zp[0][2] += hv.z * p.x; zp[0][3] += hv.z * p.y;
            p = upk_fp8(q0.w, false); zp[0][0] += hv.w * p.x; zp[0][1] += hv.w * p.y;
            p = upk_fp8(q0.w, true);  zp[0][2] += hv.w * p.x; zp[0][3] += hv.w * p.y;

            p = upk_fp8(q1.x, false); zp[1][0] += hv.x * p.x; zp[1][1] += hv.x * p.y;
            p = upk_fp8(q1.x, true);  zp[1][2] += hv.x * p.x; zp[1][3] += hv.x * p.y;
            p = upk_fp8(q1.y, false); zp[1][0] += hv.y * p.x; zp[1][1] += hv.y * p.y;
            p = upk_fp8(q1.y, true);  zp[1][2] += hv.y * p.x; zp[1][3] += hv.y * p.y;
            p = upk_fp8(q1.z, false); zp[1][0] += hv.z * p.x; zp[1][1] += hv.z * p.y;
            p = upk_fp8(q1.z, true);  zp[1][2] += hv.z * p.x; zp[1][3] += hv.z * p.y;
            p = upk_fp8(q1.w, false); zp[1][0] += hv.w * p.x; zp[1][1] += hv.w * p.y;
            p = upk_fp8(q1.w, true);  zp[1][2] += hv.w * p.x; zp[1][3] += hv.w * p.y;

            p = upk_fp8(q2.x, false); zp[2][0] += hv.x * p.x; zp[2][1] += hv.x * p.y;
            p = upk_fp8(q2.x, true);  zp[2][2] += hv.x * p.x; zp[2][3] += hv.x * p.y;
            p = upk_fp8(q2.y, false); zp[2][0] += hv.y * p.x; zp[2][1] += hv.y * p.y;
            p = upk_fp8(q2.y, true);  zp[2][2] += hv.y * p.x; zp[2][3] += hv.y * p.y;
            p = upk_fp8(q2.z, false); zp[2][0] += hv.z * p.x; zp[2][1] += hv.z * p.y;
            p = upk_fp8(q2.z, true);  zp[2][2] += hv.z * p.x; zp[2][3] += hv.z * p.y;
            p = upk_fp8(q2.w, false); zp[2][0] += hv.w * p.x; zp[2][1] += hv.w * p.y;
            p = upk_fp8(q2.w, true);  zp[2][2] += hv.w * p.x; zp[2][3] += hv.w * p.y;
        }
    }
#pragma unroll
    for (int off = 32; off; off >>= 1) {
#pragma unroll
        for (int kk = 0; kk < TOPK; ++kk)
#pragma unroll
            for (int r = 0; r < RNK; ++r)
                zp[kk][r] += __shfl_down(zp[kk][r], off);
    }
    if (lane == 0) {
#pragma unroll
        for (int kk = 0; kk < TOPK; ++kk)
#pragma unroll
            for (int r = 0; r < RNK; ++r)
                redz[wid][kk * RNK + r] = zp[kk][r];
    }
    __syncthreads();   // barrier 2 of 2

    // ---- zf: every thread, left-assoc cross-wave sum (r7) ----
    float zf_[12];
#pragma unroll
    for (int t = 0; t < 12; ++t)
        zf_[t] = redz[0][t] + redz[1][t] + redz[2][t] + redz[3][t];

    // ---- out = (h - temb) + delta (h from LDS; r7 delta expression) ----
#pragma unroll
    for (int k = 0; k < 4; ++k) {
        int i4 = tid + k * 256;
        int e = i4 * 4;          // all 4 elements in the same 32-block
        int bb = e >> 5;
        f4 hh = reinterpret_cast<const f4*>(h_lds)[i4];
        f4 tt = tr4[i4];
        f4 o = hh - tt;
        int kk = (bb == n0) ? 0 : (bb == n1) ? 1 : (bb == n2) ? 2 : -1;
        if (kk >= 0) {
            int nn = (kk == 0) ? n0 : (kk == 1) ? n1 : n2;
            float za = (kk == 0) ? zf_[0] : (kk == 1) ? zf_[4] : zf_[8];
            float zb = (kk == 0) ? zf_[1] : (kk == 1) ? zf_[5] : zf_[9];
            float zc = (kk == 0) ? zf_[2] : (kk == 1) ? zf_[6] : zf_[10];
            float zd = (kk == 0) ? zf_[3] : (kk == 1) ? zf_[7] : zf_[11];
            float gg = (kk == 0) ? g0 : (kk == 1) ? g1 : g2;
            const float* bm = Bm + (size_t)nn * 128;
            int c = e & 31;
            float d0 = za * bm[c + 0] + zb * bm[32 + c + 0] + zc * bm[64 + c + 0] + zd * bm[96 + c + 0];
            float d1 = za * bm[c + 1] + zb * bm[32 + c + 1] + zc * bm[64 + c + 1] + zd * bm[96 + c + 1];
            float d2 = za * bm[c + 2] + zb * bm[32 + c + 2] + zc * bm[64 + c + 2] + zd * bm[96 + c + 2];
            float d3 = za * bm[c + 3] + zb * bm[32 + c + 3] + zc * bm[64 + c + 3] + zd * bm[96 + c + 3];
            o.x += d0 * gg;
            o.y += d1 * gg;
            o.z += d2 * gg;
            o.w += d3 * gg;
        }
        __builtin_nontemporal_store(o, or4 + i4);
    }
}

extern "C" void kernel_launch(void* const* d_in, const int* in_sizes, int n_in,
                              void* d_out, int out_size, void* d_ws, size_t ws_size,
                              hipStream_t stream) {
    const float* x        = (const float*)d_in[0];
    const int*   task_ids = (const int*)  d_in[1];
    const float* task_emb = (const float*)d_in[2];
    const float* Wp       = (const float*)d_in[3];
    const float* bp       = (const float*)d_in[4];
    const float* centers  = (const float*)d_in[5];
    const float* A        = (const float*)d_in[6];
    const float* Bm       = (const float*)d_in[7];
    const float* scale    = (const float*)d_in[8];

    int tokens = in_sizes[0] / HDIM;   // B*S
    int B      = in_sizes[1];
    int S      = tokens / B;

    u32* Af8 = (u32*)d_ws;             // 2 MiB (ws >= 4 MiB proven earlier)

    const int n_u4 = NBLK * HDIM * RNK / 16;     // 131072 u4s
    convert_A8<<<dim3(n_u4 / 256), dim3(256), 0, stream>>>(A, Af8);
    npl_fused<<<dim3(tokens), dim3(256), 0, stream>>>(
        x, task_ids, task_emb, Wp, bp, centers, Af8, Bm, scale,
        (float*)d_out, S);
}